// Round 2
// baseline (1327.931 us; speedup 1.0000x reference)
//
#include <hip/hip_runtime.h>

#define N_NODES 50000
#define N_EDGES 800000
#define IN_F    128
#define HID_F   304

// ---------------- degree count ----------------
__global__ void k_degrees(const int* __restrict__ src, const int* __restrict__ dst,
                          int* __restrict__ deg_out, int* __restrict__ deg_in) {
    int e = blockIdx.x * blockDim.x + threadIdx.x;
    if (e < N_EDGES) {
        atomicAdd(&deg_out[src[e]], 1);
        atomicAdd(&deg_in[dst[e]], 1);
    }
}

// ---------------- single-block exclusive scan of deg_in -> row_off, cursor ----------------
__global__ __launch_bounds__(1024) void k_scan(const int* __restrict__ deg_in,
                                               int* __restrict__ row_off,
                                               int* __restrict__ cursor) {
    __shared__ int ssum[1024];
    const int T = 1024;
    int tid = threadIdx.x;
    const int per = (N_NODES + T - 1) / T;   // 49
    int start = tid * per;
    int end = start + per; if (end > N_NODES) end = N_NODES;
    int s = 0;
    for (int i = start; i < end; i++) s += deg_in[i];
    ssum[tid] = s;
    __syncthreads();
    for (int ofs = 1; ofs < T; ofs <<= 1) {
        int v = 0;
        if (tid >= ofs) v = ssum[tid - ofs];
        __syncthreads();
        if (tid >= ofs) ssum[tid] += v;
        __syncthreads();
    }
    int run = (tid == 0) ? 0 : ssum[tid - 1];
    for (int i = start; i < end; i++) {
        row_off[i] = run;
        cursor[i] = run;
        run += deg_in[i];
    }
}

// ---------------- CSR fill ----------------
__global__ void k_fill(const int* __restrict__ src, const int* __restrict__ dst,
                       int* __restrict__ cursor, int* __restrict__ csr_src) {
    int e = blockIdx.x * blockDim.x + threadIdx.x;
    if (e < N_EDGES) {
        int p = atomicAdd(&cursor[dst[e]], 1);
        csr_src[p] = src[e];
    }
}

// ---------------- prescale: xs = x * inv_out (f32, float4 vectorized) ----------------
__global__ void k_prescale(const float* __restrict__ x, const int* __restrict__ deg_out,
                           float* __restrict__ xs) {
    int gid = blockIdx.x * blockDim.x + threadIdx.x;   // over N*32 float4
    if (gid >= N_NODES * 32) return;
    int n = gid >> 5;
    int d = deg_out[n]; if (d < 1) d = 1;
    float s = rsqrtf((float)d);
    float4 v = ((const float4*)x)[gid];
    v.x *= s; v.y *= s; v.z *= s; v.w *= s;
    ((float4*)xs)[gid] = v;
}

// ---------------- gather: t[n] = inv_in[n] * sum over in-edges of xs[src] ----------------
// one wave per node; each lane owns a float2 (128 floats / 64 lanes)
__global__ __launch_bounds__(256) void k_gather(const float* __restrict__ xs,
                                                const int* __restrict__ row_off,
                                                const int* __restrict__ deg_in,
                                                const int* __restrict__ csr_src,
                                                float* __restrict__ tbuf) {
    int node = blockIdx.x * 4 + (threadIdx.x >> 6);
    int lane = threadIdx.x & 63;
    if (node >= N_NODES) return;
    int off = __builtin_amdgcn_readfirstlane(row_off[node]);
    int deg = __builtin_amdgcn_readfirstlane(deg_in[node]);
    const float2* xu = (const float2*)xs;
    float a0 = 0.f, a1 = 0.f;
    int j = 0;
    for (; j + 4 <= deg; j += 4) {
        int s0 = csr_src[off + j + 0];
        int s1 = csr_src[off + j + 1];
        int s2 = csr_src[off + j + 2];
        int s3 = csr_src[off + j + 3];
        float2 v0 = xu[s0 * 64 + lane];
        float2 v1 = xu[s1 * 64 + lane];
        float2 v2 = xu[s2 * 64 + lane];
        float2 v3 = xu[s3 * 64 + lane];
        a0 += v0.x + v1.x + v2.x + v3.x;
        a1 += v0.y + v1.y + v2.y + v3.y;
    }
    for (; j < deg; j++) {
        int s = csr_src[off + j];
        float2 v = xu[s * 64 + lane];
        a0 += v.x;
        a1 += v.y;
    }
    int d = deg; if (d < 1) d = 1;
    float sc = rsqrtf((float)d);
    float2 r; r.x = a0 * sc; r.y = a1 * sc;
    ((float2*)tbuf)[node * 64 + lane] = r;
}

// ---------------- GEMM (t @ W) + bias + relu + global sum ----------------
// block: 256 threads, 64 nodes, col chunks of 32, K=128.
// each thread: 2 nodes x 4 cols.
#define GM 64
#define TPAD 132   // row stride for t_s (16B-aligned, mod 32 = 4 -> conflict-free node reads)
__global__ __launch_bounds__(256) void k_gemm(const float* __restrict__ tbuf,
                                              const float* __restrict__ W,
                                              const float* __restrict__ bias,
                                              float* __restrict__ gsum) {
    __shared__ float t_s[GM * TPAD];     // 64 x 128 (padded)
    __shared__ float w_s[128 * 32];      // W chunk
    __shared__ float wred[4];

    int tid = threadIdx.x;
    int n0 = blockIdx.x * GM;

    // stage t tile (float4, coalesced)
    #pragma unroll
    for (int i = 0; i < GM * 32 / 256; i++) {    // 8 float4 per thread
        int id = tid + 256 * i;
        int r = id >> 5, c4 = id & 31;
        float4 v = make_float4(0.f, 0.f, 0.f, 0.f);
        if (n0 + r < N_NODES) v = ((const float4*)tbuf)[(n0 + r) * 32 + c4];
        *(float4*)&t_s[r * TPAD + c4 * 4] = v;
    }

    int tx = tid & 7;          // col quad (4 cols)
    int ty = tid >> 3;         // node pair
    int nA = ty * 2, nB = ty * 2 + 1;

    float ssum = 0.f;
    for (int ch = 0; ch < 10; ch++) {
        int cc = ch * 32;
        __syncthreads();
        // stage W chunk [128 x 32]
        #pragma unroll
        for (int i = 0; i < 128 * 32 / 256; i++) {
            int id = tid + 256 * i;
            int k = id >> 5, jj = id & 31;
            int col = cc + jj;
            float v = 0.f;
            if (col < HID_F) v = W[k * HID_F + col];
            w_s[k * 32 + jj] = v;
        }
        __syncthreads();

        float acc0[4] = {0.f, 0.f, 0.f, 0.f};
        float acc1[4] = {0.f, 0.f, 0.f, 0.f};
        const float* tA = &t_s[nA * TPAD];
        const float* tB = &t_s[nB * TPAD];
        #pragma unroll 8
        for (int k = 0; k < 128; k++) {
            float a = tA[k];
            float b = tB[k];
            float4 w = *(const float4*)&w_s[k * 32 + tx * 4];
            acc0[0] += a * w.x; acc0[1] += a * w.y; acc0[2] += a * w.z; acc0[3] += a * w.w;
            acc1[0] += b * w.x; acc1[1] += b * w.y; acc1[2] += b * w.z; acc1[3] += b * w.w;
        }
        bool vA = (n0 + nA < N_NODES);
        bool vB = (n0 + nB < N_NODES);
        #pragma unroll
        for (int c = 0; c < 4; c++) {
            int col = cc + tx * 4 + c;
            if (col < HID_F) {
                float bv = bias[col];
                if (vA) { float y = acc0[c] + bv; ssum += fmaxf(y, 0.f); }
                if (vB) { float y = acc1[c] + bv; ssum += fmaxf(y, 0.f); }
            }
        }
    }

    // reduce within wave then block
    for (int o = 32; o; o >>= 1) ssum += __shfl_down(ssum, o, 64);
    int wv = tid >> 6, ln = tid & 63;
    if (ln == 0) wred[wv] = ssum;
    __syncthreads();
    if (tid == 0) atomicAdd(gsum, wred[0] + wred[1] + wred[2] + wred[3]);
}

// ---------------- finalize ----------------
__global__ void k_finalize(const float* __restrict__ gsum, float* __restrict__ out) {
    out[0] = gsum[0] * (1.0f / (3.0f * N_NODES * HID_F));
}

extern "C" void kernel_launch(void* const* d_in, const int* in_sizes, int n_in,
                              void* d_out, int out_size, void* d_ws, size_t ws_size,
                              hipStream_t stream) {
    const float* x[3] = {(const float*)d_in[0], (const float*)d_in[1], (const float*)d_in[2]};
    const int* srcs[3] = {(const int*)d_in[3], (const int*)d_in[5], (const int*)d_in[7]};
    const int* dsts[3] = {(const int*)d_in[4], (const int*)d_in[6], (const int*)d_in[8]};
    const float* W = (const float*)d_in[9];
    const float* b = (const float*)d_in[10];

    char* ws = (char*)d_ws;
    int* deg_out = (int*)(ws + 0);                     // 200000 B
    int* deg_in  = (int*)(ws + 200000);                // 200000 B (contiguous after deg_out)
    int* row_off = (int*)(ws + 400000);                // 200000 B
    int* cursor  = (int*)(ws + 600000);                // 200000 B
    int* csr_src = (int*)(ws + 800000);                // 3.2 MB
    float* xs    = (float*)(ws + 4000000);             // 25.6 MB
    float* tb    = (float*)(ws + 29600000);            // 25.6 MB
    float* gsum  = (float*)(ws + 55200000);            // 4 B

    hipMemsetAsync(gsum, 0, 4, stream);
    for (int g = 0; g < 3; g++) {
        hipMemsetAsync(deg_out, 0, 2 * N_NODES * 4, stream);   // deg_out + deg_in contiguous
        k_degrees<<<N_EDGES / 256, 256, 0, stream>>>(srcs[g], dsts[g], deg_out, deg_in);
        k_scan<<<1, 1024, 0, stream>>>(deg_in, row_off, cursor);
        k_fill<<<N_EDGES / 256, 256, 0, stream>>>(srcs[g], dsts[g], cursor, csr_src);
        k_prescale<<<(N_NODES * 32 + 255) / 256, 256, 0, stream>>>(x[g], deg_out, xs);
        k_gather<<<N_NODES / 4, 256, 0, stream>>>(xs, row_off, deg_in, csr_src, tb);
        k_gemm<<<(N_NODES + GM - 1) / GM, 256, 0, stream>>>(tb, W, b, gsum);
    }
    k_finalize<<<1, 1, 0, stream>>>(gsum, (float*)d_out);
}

// Round 3
// 717.409 us; speedup vs baseline: 1.8510x; 1.8510x over previous
//
#include <hip/hip_runtime.h>

#define N_NODES 50000
#define N_EDGES 800000
#define IN_F    128
#define HID_F   304
#define NTILES  19   // 304 / 16

typedef unsigned int   uint_t;
typedef unsigned short ushort_t;
typedef __attribute__((ext_vector_type(8))) short  short8_t;
typedef __attribute__((ext_vector_type(4))) float  floatx4;

__device__ inline float bf2f(uint_t h) {
    uint_t u = h << 16; float f; __builtin_memcpy(&f, &u, 4); return f;
}
__device__ inline float bf2f_lo(uint_t v) { return bf2f(v & 0xffffu); }
__device__ inline float bf2f_hi(uint_t v) { return bf2f(v >> 16); }
__device__ inline ushort_t f2bf(float f) {
    uint_t u; __builtin_memcpy(&u, &f, 4);
    uint_t r = u + 0x7fffu + ((u >> 16) & 1u);   // RTNE
    return (ushort_t)(r >> 16);
}
__device__ inline uint_t packbf2(float a, float b) {
    return (uint_t)f2bf(a) | ((uint_t)f2bf(b) << 16);
}

// ---------------- degrees, all 3 graphs ----------------
__global__ void k_degrees_all(const int* __restrict__ s0, const int* __restrict__ d0,
                              const int* __restrict__ s1, const int* __restrict__ d1,
                              const int* __restrict__ s2, const int* __restrict__ d2,
                              int* __restrict__ deg_out, int* __restrict__ deg_in) {
    int gid = blockIdx.x * 256 + threadIdx.x;
    if (gid >= 3 * N_EDGES) return;
    int g = gid / N_EDGES;
    int e = gid - g * N_EDGES;
    const int* sp = (g == 0) ? s0 : ((g == 1) ? s1 : s2);
    const int* dp = (g == 0) ? d0 : ((g == 1) ? d1 : d2);
    atomicAdd(&deg_out[g * N_NODES + sp[e]], 1);
    atomicAdd(&deg_in [g * N_NODES + dp[e]], 1);
}

// ---------------- exclusive scan of deg_in per graph (3 blocks) ----------------
__global__ __launch_bounds__(1024) void k_scan3(const int* __restrict__ deg_in,
                                                int* __restrict__ row_off,
                                                int* __restrict__ cursor) {
    __shared__ int wsum[16];
    int g = blockIdx.x;
    const int* din = deg_in + g * N_NODES;
    int* ro = row_off + g * N_NODES;
    int* cu = cursor  + g * N_NODES;
    int tid = threadIdx.x, lane = tid & 63, wv = tid >> 6;
    int total = 0;
    for (int base = 0; base < N_NODES; base += 1024) {
        int i = base + tid;
        int v = (i < N_NODES) ? din[i] : 0;
        int inc = v;
        #pragma unroll
        for (int o = 1; o < 64; o <<= 1) {
            int u = __shfl_up(inc, o, 64);
            if (lane >= o) inc += u;
        }
        if (lane == 63) wsum[wv] = inc;
        __syncthreads();
        if (wv == 0) {
            int t2 = (lane < 16) ? wsum[lane] : 0;
            #pragma unroll
            for (int o = 1; o < 16; o <<= 1) {
                int u = __shfl_up(t2, o, 64);
                if (lane >= o) t2 += u;
            }
            if (lane < 16) wsum[lane] = t2;
        }
        __syncthreads();
        int wave_off = (wv > 0) ? wsum[wv - 1] : 0;
        int excl = total + wave_off + (inc - v);
        if (i < N_NODES) { ro[i] = excl; cu[i] = excl; }
        int bsum = wsum[15];
        __syncthreads();
        total += bsum;
    }
}

// ---------------- CSR fill, all 3 graphs ----------------
__global__ void k_fill_all(const int* __restrict__ s0, const int* __restrict__ d0,
                           const int* __restrict__ s1, const int* __restrict__ d1,
                           const int* __restrict__ s2, const int* __restrict__ d2,
                           int* __restrict__ cursor, int* __restrict__ csr_src) {
    int gid = blockIdx.x * 256 + threadIdx.x;
    if (gid >= 3 * N_EDGES) return;
    int g = gid / N_EDGES;
    int e = gid - g * N_EDGES;
    const int* sp = (g == 0) ? s0 : ((g == 1) ? s1 : s2);
    const int* dp = (g == 0) ? d0 : ((g == 1) ? d1 : d2);
    int p = atomicAdd(&cursor[g * N_NODES + dp[e]], 1);
    csr_src[g * N_EDGES + p] = sp[e];
}

// ---------------- prescale: xs = bf16(x * inv_out) ----------------
__global__ void k_prescale(const float* __restrict__ x, const int* __restrict__ dout,
                           ushort_t* __restrict__ xs) {
    int gid = blockIdx.x * 256 + threadIdx.x;   // over N*32 float4
    if (gid >= N_NODES * 32) return;
    int n = gid >> 5;
    int d = dout[n]; if (d < 1) d = 1;
    float s = rsqrtf((float)d);
    float4 v = ((const float4*)x)[gid];
    uint2 o;
    o.x = packbf2(v.x * s, v.y * s);
    o.y = packbf2(v.z * s, v.w * s);
    ((uint2*)xs)[gid] = o;
}

// ---------------- gather (bf16 rows, f32 accumulate) ----------------
__global__ __launch_bounds__(256) void k_gather(const ushort_t* __restrict__ xs,
                                                const int* __restrict__ row_off,
                                                const int* __restrict__ deg_in,
                                                const int* __restrict__ csr,
                                                ushort_t* __restrict__ tb) {
    int node = blockIdx.x * 4 + (threadIdx.x >> 6);
    int lane = threadIdx.x & 63;
    if (node >= N_NODES) return;
    int off = __builtin_amdgcn_readfirstlane(row_off[node]);
    int deg = __builtin_amdgcn_readfirstlane(deg_in[node]);
    const uint_t* xu = (const uint_t*)xs;
    float a0 = 0.f, a1 = 0.f;
    int j = 0;
    for (; j + 4 <= deg; j += 4) {
        int s0 = csr[off + j + 0];
        int s1 = csr[off + j + 1];
        int s2 = csr[off + j + 2];
        int s3 = csr[off + j + 3];
        uint_t v0 = xu[s0 * 64 + lane];
        uint_t v1 = xu[s1 * 64 + lane];
        uint_t v2 = xu[s2 * 64 + lane];
        uint_t v3 = xu[s3 * 64 + lane];
        a0 += bf2f_lo(v0) + bf2f_lo(v1) + bf2f_lo(v2) + bf2f_lo(v3);
        a1 += bf2f_hi(v0) + bf2f_hi(v1) + bf2f_hi(v2) + bf2f_hi(v3);
    }
    for (; j < deg; j++) {
        int s = csr[off + j];
        uint_t v = xu[s * 64 + lane];
        a0 += bf2f_lo(v);
        a1 += bf2f_hi(v);
    }
    int d = deg < 1 ? 1 : deg;
    float sc = rsqrtf((float)d);
    ((uint_t*)tb)[node * 64 + lane] = packbf2(a0 * sc, a1 * sc);
}

// ---------------- pack W into B-fragment layout (bf16), once ----------------
// Wp[((ct*4 + kk)*64 + lane)*8 + j] = bf16( W[(kk*32 + (lane>>4)*8 + j) * HID_F + ct*16 + (lane&15)] )
__global__ void k_prepW(const float* __restrict__ W, ushort_t* __restrict__ Wp) {
    int gid = blockIdx.x * 256 + threadIdx.x;   // NTILES*4*64 = 4864 groups
    if (gid >= NTILES * 4 * 64) return;
    int ct   = gid >> 8;
    int rem  = gid & 255;
    int kk   = rem >> 6;
    int lane = rem & 63;
    int col   = ct * 16 + (lane & 15);
    int kbase = kk * 32 + (lane >> 4) * 8;
    uint_t o[4];
    #pragma unroll
    for (int p = 0; p < 4; p++) {
        float f0 = W[(kbase + 2 * p)     * HID_F + col];
        float f1 = W[(kbase + 2 * p + 1) * HID_F + col];
        o[p] = packbf2(f0, f1);
    }
    *(uint4*)(Wp + gid * 8) = make_uint4(o[0], o[1], o[2], o[3]);
}

// ---------------- MFMA GEMM (t @ W) + bias + relu + global sum ----------------
// 256 threads = 4 waves; block covers 64 nodes; wave w -> rows [w*16, w*16+16).
#define TSTRIDE 136   // 128 + 8 bf16 pad -> 2-way LDS conflicts only (free)
__global__ __launch_bounds__(256) void k_gemm(const ushort_t* __restrict__ tb,
                                              const ushort_t* __restrict__ Wp,
                                              const float* __restrict__ bias,
                                              float* __restrict__ gsum) {
    __shared__ ushort_t t_s[64 * TSTRIDE];
    __shared__ float b_s[HID_F];
    __shared__ float wred[4];

    int tid = threadIdx.x;
    int n0 = blockIdx.x * 64;

    // stage t tile: 64 rows x 128 bf16, as 1024 16B chunks
    #pragma unroll
    for (int i = 0; i < 4; i++) {
        int id = tid + 256 * i;
        int r = id >> 4, c = id & 15;      // c = 16B chunk (8 bf16)
        uint4 v = make_uint4(0, 0, 0, 0);
        if (n0 + r < N_NODES) v = *(const uint4*)(tb + (n0 + r) * 128 + c * 8);
        *(uint4*)(&t_s[r * TSTRIDE + c * 8]) = v;
    }
    if (tid < HID_F / 4) ((float4*)b_s)[tid] = ((const float4*)bias)[tid];
    __syncthreads();

    int wv = tid >> 6, lane = tid & 63;
    int m = lane & 15, quad = lane >> 4;

    // A fragments: A[m][k], k = kk*32 + quad*8 + j  (m89-verified layout)
    const ushort_t* ap = &t_s[(wv * 16 + m) * TSTRIDE + quad * 8];
    short8_t a0 = *(const short8_t*)(ap);
    short8_t a1 = *(const short8_t*)(ap + 32);
    short8_t a2 = *(const short8_t*)(ap + 64);
    short8_t a3 = *(const short8_t*)(ap + 96);

    float ssum = 0.f;
    int row_base = n0 + wv * 16 + quad * 4;

    for (int ct = 0; ct < NTILES; ct++) {
        const ushort_t* w0 = Wp + ((ct * 4) * 64 + lane) * 8;
        short8_t b0 = *(const short8_t*)(w0);
        short8_t b1 = *(const short8_t*)(w0 + 512);
        short8_t b2 = *(const short8_t*)(w0 + 1024);
        short8_t b3 = *(const short8_t*)(w0 + 1536);
        floatx4 acc = {0.f, 0.f, 0.f, 0.f};
        acc = __builtin_amdgcn_mfma_f32_16x16x32_bf16(a0, b0, acc, 0, 0, 0);
        acc = __builtin_amdgcn_mfma_f32_16x16x32_bf16(a1, b1, acc, 0, 0, 0);
        acc = __builtin_amdgcn_mfma_f32_16x16x32_bf16(a2, b2, acc, 0, 0, 0);
        acc = __builtin_amdgcn_mfma_f32_16x16x32_bf16(a3, b3, acc, 0, 0, 0);
        float bv = b_s[ct * 16 + m];
        #pragma unroll
        for (int r = 0; r < 4; r++) {
            if (row_base + r < N_NODES) {
                float y = acc[r] + bv;        // C/D: col=lane&15, row=quad*4+r
                ssum += fmaxf(y, 0.f);
            }
        }
    }

    #pragma unroll
    for (int o = 32; o; o >>= 1) ssum += __shfl_down(ssum, o, 64);
    if (lane == 0) wred[wv] = ssum;
    __syncthreads();
    if (tid == 0) atomicAdd(gsum, wred[0] + wred[1] + wred[2] + wred[3]);
}

// ---------------- finalize ----------------
__global__ void k_finalize(const float* __restrict__ gsum, float* __restrict__ out) {
    out[0] = gsum[0] * (1.0f / (3.0f * N_NODES * HID_F));
}

extern "C" void kernel_launch(void* const* d_in, const int* in_sizes, int n_in,
                              void* d_out, int out_size, void* d_ws, size_t ws_size,
                              hipStream_t stream) {
    const float* x[3] = {(const float*)d_in[0], (const float*)d_in[1], (const float*)d_in[2]};
    const int* srcs[3] = {(const int*)d_in[3], (const int*)d_in[5], (const int*)d_in[7]};
    const int* dsts[3] = {(const int*)d_in[4], (const int*)d_in[6], (const int*)d_in[8]};
    const float* W = (const float*)d_in[9];
    const float* b = (const float*)d_in[10];

    char* ws = (char*)d_ws;
    int* deg_out     = (int*)(ws + 0);                 // 3*200000 = 600000
    int* deg_in      = (int*)(ws + 600000);            // 600000 (contiguous after deg_out)
    int* row_off     = (int*)(ws + 1200000);           // 600000
    int* cursor      = (int*)(ws + 1800000);           // 600000
    int* csr         = (int*)(ws + 2400000);           // 9.6 MB
    ushort_t* xs     = (ushort_t*)(ws + 12000000);     // 12.8 MB (one graph at a time)
    ushort_t* tb     = (ushort_t*)(ws + 24800000);     // 12.8 MB
    ushort_t* Wp     = (ushort_t*)(ws + 37600000);     // 77824 B
    float* gsum      = (float*)(ws + 37680000);        // 4 B

    hipMemsetAsync(deg_out, 0, 2 * 3 * N_NODES * 4, stream);
    hipMemsetAsync(gsum, 0, 4, stream);

    k_prepW<<<(NTILES * 4 * 64 + 255) / 256, 256, 0, stream>>>(W, Wp);
    k_degrees_all<<<(3 * N_EDGES + 255) / 256, 256, 0, stream>>>(
        srcs[0], dsts[0], srcs[1], dsts[1], srcs[2], dsts[2], deg_out, deg_in);
    k_scan3<<<3, 1024, 0, stream>>>(deg_in, row_off, cursor);
    k_fill_all<<<(3 * N_EDGES + 255) / 256, 256, 0, stream>>>(
        srcs[0], dsts[0], srcs[1], dsts[1], srcs[2], dsts[2], cursor, csr);

    for (int g = 0; g < 3; g++) {
        k_prescale<<<(N_NODES * 32 + 255) / 256, 256, 0, stream>>>(
            x[g], deg_out + g * N_NODES, xs);
        k_gather<<<(N_NODES + 3) / 4, 256, 0, stream>>>(
            xs, row_off + g * N_NODES, deg_in + g * N_NODES, csr + g * N_EDGES, tb);
        k_gemm<<<(N_NODES + 63) / 64, 256, 0, stream>>>(tb, Wp, b, gsum);
    }
    k_finalize<<<1, 1, 0, stream>>>(gsum, (float*)d_out);
}